// Round 10
// baseline (167.979 us; speedup 1.0000x reference)
//
#include <hip/hip_runtime.h>
#include <hip/hip_bf16.h>
#include <math.h>

// ---------------------------------------------------------------------------
// TGCN: z/r/h GCN gates + GRU + readout.
// R1: segment_sum(w * (x@W)[src]) == segment_sum(w * x[src]) @ W
//     -> aggregate raw features ONCE (AX), fold W_g into Wl_g top half.
// R2: gate GEMMs on MFMA (bf16 in, f32 acc); weights pre-fused in d_ws.
// R3-R9 scatter lessons (measured):
//   - atomic drain is PAYLOAD-BYTE bound ~1.3TB/s (R3: 25.6M dwords=85us;
//     R8: 12.8M u64 same bytes=76us) -> request count secondary.
//   - scattered sub-line stores cost one 64B line each -> restructure >= 65us.
// R10: hypothesis = the 1.3TB/s is cross-XCD line ping-pong on shared AXb.
//     Test: 8 XCD-private bf16 replicas (rep = blockIdx & 7); atomics stay
//     XCD-local; gates sums replicas in f32 during staging. nrep auto-halves
//     to fit ws (nrep=1 == R9 exactly).
// ---------------------------------------------------------------------------

typedef __attribute__((ext_vector_type(8))) short bf16x8;   // 8 bf16 = 4 VGPR
typedef __attribute__((ext_vector_type(4))) float f32x4;    // MFMA C/D

static __device__ __forceinline__ short f2bf(float x) {
    union { float f; unsigned u; } v; v.f = x;
    unsigned r = v.u + 0x7fffu + ((v.u >> 16) & 1u);        // RNE
    return (short)(r >> 16);
}
static __device__ __forceinline__ float bf2f(short s) {
    return __uint_as_float((unsigned)(unsigned short)s << 16);
}
__device__ __forceinline__ float sigmoid_(float x) { return 1.0f / (1.0f + __expf(-x)); }
__device__ __forceinline__ float tanh_(float x)    { return 1.0f - 2.0f / (__expf(2.0f * x) + 1.0f); }

// blocks 0..3: fuse weights; blocks 4..: zero the replica accumulators.
// WT[m][64][64] bf16 n-major, m=0..2: W_g@Wl_g_top; 3..5: Wl_g_bot; 6: W_out
// bfv[4][64] f32 fused biases.
__global__ __launch_bounds__(256) void prep_fuse_kernel(
    const float* __restrict__ Wz, const float* __restrict__ Wr, const float* __restrict__ Wh,
    const float* __restrict__ bz, const float* __restrict__ br, const float* __restrict__ bh,
    const float* __restrict__ Wlz, const float* __restrict__ Wlr, const float* __restrict__ Wlh,
    const float* __restrict__ blz, const float* __restrict__ blr, const float* __restrict__ blh,
    const float* __restrict__ Wout, const float* __restrict__ bout_,
    short* __restrict__ WT, float* __restrict__ bfv,
    short* __restrict__ AXrep, int n16total)
{
    int g = blockIdx.x;
    int tid = threadIdx.x;
    if (g >= 4) {                       // ---- zero path
        int i = (g - 4) * 256 + tid;
        int stride = (gridDim.x - 4) * 256;
        const uint4 z = make_uint4(0, 0, 0, 0);
        for (; i < n16total; i += stride) ((uint4*)AXrep)[i] = z;
        return;
    }
    if (g == 3) {                       // ---- W_out transpose
        for (int i = tid; i < 4096; i += 256) {
            int k = i >> 6, n = i & 63;
            WT[6 * 4096 + n * 64 + k] = f2bf(Wout[k * 64 + n]);
        }
        if (tid < 64) bfv[192 + tid] = bout_[tid];
        return;
    }
    const float* Win = (g == 0) ? Wz : (g == 1) ? Wr : Wh;
    const float* Wl  = (g == 0) ? Wlz : (g == 1) ? Wlr : Wlh;
    const float* b   = (g == 0) ? bz : (g == 1) ? br : bh;
    const float* bl  = (g == 0) ? blz : (g == 1) ? blr : blh;

    __shared__ float wl_s[64][65];
    for (int i = tid; i < 4096; i += 256) wl_s[i >> 6][i & 63] = Wl[i];
    __syncthreads();

    int k = tid >> 2;
    int j0 = (tid & 3) << 4;
    float acc[16];
#pragma unroll
    for (int jj = 0; jj < 16; jj++) acc[jj] = 0.f;
    for (int t = 0; t < 64; t++) {
        float a = Win[k * 64 + t];
#pragma unroll
        for (int jj = 0; jj < 16; jj++) acc[jj] = fmaf(a, wl_s[t][j0 + jj], acc[jj]);
    }
#pragma unroll
    for (int jj = 0; jj < 16; jj++) WT[g * 4096 + (j0 + jj) * 64 + k] = f2bf(acc[jj]);

    for (int i = tid; i < 4096; i += 256) {        // bottom half of Wl, transposed
        int kk = i >> 6, n = i & 63;
        WT[(3 + g) * 4096 + n * 64 + kk] = f2bf(Wl[(64 + kk) * 64 + n]);
    }
    if (tid < 64) {
        float a2 = bl[tid];
        for (int t = 0; t < 64; t++) a2 = fmaf(b[t], wl_s[t][tid], a2);
        bfv[g * 64 + tid] = a2;
    }
}

// AXrep[blockIdx&mask][dst] += bf16(w * x[src]) — one half-wave per edge.
// Replica per XCD (block round-robin) keeps atomic lines XCD-local.
__global__ __launch_bounds__(256) void scatter_kernel(
    const float* __restrict__ x, const float* __restrict__ ew,
    const int* __restrict__ ei, short* __restrict__ AXrep,
    int E, int N, int repMask)
{
    int e  = (blockIdx.x * 256 + threadIdx.x) >> 5;   // edge id
    int lj = threadIdx.x & 31;                        // feature pair
    if (e < E) {
        int src = ei[e];
        int dst = ei[E + e];
        float w = ew[e];
        float2 xv = *(const float2*)(x + (size_t)src * 64 + lj * 2);
        unsigned pk = (unsigned)(unsigned short)f2bf(xv.x * w)
                    | ((unsigned)(unsigned short)f2bf(xv.y * w) << 16);
        size_t rep = (size_t)(blockIdx.x & repMask);
        short* addr = AXrep + (rep * N + dst) * 64 + lj * 2;
        asm volatile("global_atomic_pk_add_bf16 %0, %1, off"
                     :: "v"(addr), "v"(pk) : "memory");
    }
    asm volatile("s_waitcnt vmcnt(0)" ::: "memory");   // drain before endpgm
}

// Fused GRU gates + readout via MFMA. 64-node tile, 4 waves, 27.6KB LDS.
// Stages AX by summing the nrep replicas in f32.
__global__ __launch_bounds__(256) void gates_kernel(
    const short* __restrict__ AXrep, int nrep,
    const float* __restrict__ hid,
    const short* __restrict__ WT, const float* __restrict__ bfv,
    float* __restrict__ outY, float* __restrict__ outH, int nNodes)
{
    __shared__ short axs[64][72];   // AX tile bf16 (reused for relu(h))
    __shared__ short hs [64][72];   // hid tile bf16
    __shared__ short rsb[64][72];   // r * hid bf16

    const int tid  = threadIdx.x;
    const int w    = tid >> 6;
    const int lane = tid & 63;
    const int lr   = lane & 15;
    const int lg   = lane >> 4;
    const int col  = w * 16 + lr;
    const int n0   = blockIdx.x * 64;

    // ---- stage AX (sum replicas, f32) and hid (f32 -> bf16)
    {
        int row = tid >> 2;
        int c0  = (tid & 3) << 4;
        int n   = n0 + row;
        bool valid = n < nNodes;
        const float4 z4 = make_float4(0.f, 0.f, 0.f, 0.f);
        float axf[16];
#pragma unroll
        for (int j = 0; j < 16; j++) axf[j] = 0.f;
        if (valid) {
            for (int r = 0; r < nrep; r++) {
                const short* base = AXrep + ((size_t)r * nNodes + n) * 64 + c0;
                bf16x8 a0 = *(const bf16x8*)(base);
                bf16x8 a1 = *(const bf16x8*)(base + 8);
#pragma unroll
                for (int j = 0; j < 8; j++) {
                    axf[j]     += bf2f(a0[j]);
                    axf[8 + j] += bf2f(a1[j]);
                }
            }
        }
#pragma unroll
        for (int j = 0; j < 16; j++) axs[row][c0 + j] = f2bf(axf[j]);
#pragma unroll
        for (int q = 0; q < 4; q++) {
            float4 vh = valid ? *(const float4*)(hid + (size_t)n * 64 + c0 + q * 4) : z4;
            int c = c0 + q * 4;
            hs[row][c + 0] = f2bf(vh.x); hs[row][c + 1] = f2bf(vh.y);
            hs[row][c + 2] = f2bf(vh.z); hs[row][c + 3] = f2bf(vh.w);
        }
    }

    // ---- B-operand fragments for all 7 matrices (56 VGPR)
    bf16x8 wf[7][2];
#pragma unroll
    for (int m = 0; m < 7; m++)
#pragma unroll
        for (int kb = 0; kb < 2; kb++)
            wf[m][kb] = *(const bf16x8*)(WT + m * 4096 + col * 64 + kb * 32 + lg * 8);
    const float bz_ = bfv[col], br_ = bfv[64 + col], bh_ = bfv[128 + col], bo_ = bfv[192 + col];

    __syncthreads();

    const f32x4 zero4 = {0.f, 0.f, 0.f, 0.f};
    f32x4 accz[4], accr[4], acch[4];
#pragma unroll
    for (int rt = 0; rt < 4; rt++) { accz[rt] = zero4; accr[rt] = zero4; acch[rt] = zero4; }

    // ---- phase A: AX-part of z,r,h and hid-part of z,r
#pragma unroll
    for (int rt = 0; rt < 4; rt++) {
        int arow = rt * 16 + lr;
#pragma unroll
        for (int kb = 0; kb < 2; kb++) {
            bf16x8 aa = *(const bf16x8*)(&axs[arow][kb * 32 + lg * 8]);
            bf16x8 ah = *(const bf16x8*)(&hs [arow][kb * 32 + lg * 8]);
            accz[rt] = __builtin_amdgcn_mfma_f32_16x16x32_bf16(aa, wf[0][kb], accz[rt], 0, 0, 0);
            accr[rt] = __builtin_amdgcn_mfma_f32_16x16x32_bf16(aa, wf[1][kb], accr[rt], 0, 0, 0);
            acch[rt] = __builtin_amdgcn_mfma_f32_16x16x32_bf16(aa, wf[2][kb], acch[rt], 0, 0, 0);
            accz[rt] = __builtin_amdgcn_mfma_f32_16x16x32_bf16(ah, wf[3][kb], accz[rt], 0, 0, 0);
            accr[rt] = __builtin_amdgcn_mfma_f32_16x16x32_bf16(ah, wf[4][kb], accr[rt], 0, 0, 0);
        }
    }

    // ---- z, r; rsb <- bf16(r * hid)
    float zf[16];
#pragma unroll
    for (int rt = 0; rt < 4; rt++) {
#pragma unroll
        for (int i = 0; i < 4; i++) {
            int row = rt * 16 + lg * 4 + i;
            float z = sigmoid_(accz[rt][i] + bz_);
            float r = sigmoid_(accr[rt][i] + br_);
            zf[rt * 4 + i] = z;
            rsb[row][col] = f2bf(r * bf2f(hs[row][col]));
        }
    }
    __syncthreads();

    // ---- phase B: h_tilde += (r*hid) @ Wlh_bot ; h ; relu(h) -> axs
#pragma unroll
    for (int rt = 0; rt < 4; rt++) {
        int arow = rt * 16 + lr;
#pragma unroll
        for (int kb = 0; kb < 2; kb++) {
            bf16x8 ar = *(const bf16x8*)(&rsb[arow][kb * 32 + lg * 8]);
            acch[rt] = __builtin_amdgcn_mfma_f32_16x16x32_bf16(ar, wf[5][kb], acch[rt], 0, 0, 0);
        }
    }
#pragma unroll
    for (int rt = 0; rt < 4; rt++) {
#pragma unroll
        for (int i = 0; i < 4; i++) {
            int row = rt * 16 + lg * 4 + i;
            float ht = tanh_(acch[rt][i] + bh_);
            float z  = zf[rt * 4 + i];
            float hv = z * bf2f(hs[row][col]) + (1.f - z) * ht;
            int n = n0 + row;
            if (n < nNodes) outH[(size_t)n * 64 + col] = hv;
            axs[row][col] = f2bf(fmaxf(hv, 0.f));
        }
    }
    __syncthreads();

    // ---- phase C: y = relu(h) @ W_out + b_out
    f32x4 accy[4];
#pragma unroll
    for (int rt = 0; rt < 4; rt++) accy[rt] = zero4;
#pragma unroll
    for (int rt = 0; rt < 4; rt++) {
        int arow = rt * 16 + lr;
#pragma unroll
        for (int kb = 0; kb < 2; kb++) {
            bf16x8 aa = *(const bf16x8*)(&axs[arow][kb * 32 + lg * 8]);
            accy[rt] = __builtin_amdgcn_mfma_f32_16x16x32_bf16(aa, wf[6][kb], accy[rt], 0, 0, 0);
        }
    }
#pragma unroll
    for (int rt = 0; rt < 4; rt++) {
#pragma unroll
        for (int i = 0; i < 4; i++) {
            int row = rt * 16 + lg * 4 + i;
            int n = n0 + row;
            if (n < nNodes) outY[(size_t)n * 64 + col] = accy[rt][i] + bo_;
        }
    }
}

extern "C" void kernel_launch(void* const* d_in, const int* in_sizes, int n_in,
                              void* d_out, int out_size, void* d_ws, size_t ws_size,
                              hipStream_t stream)
{
    const float* node_feat = (const float*)d_in[0];
    const float* edge_w    = (const float*)d_in[1];
    const float* hidden    = (const float*)d_in[2];
    const float* W_z  = (const float*)d_in[3];
    const float* b_z  = (const float*)d_in[4];
    const float* W_r  = (const float*)d_in[5];
    const float* b_r  = (const float*)d_in[6];
    const float* W_h  = (const float*)d_in[7];
    const float* b_h  = (const float*)d_in[8];
    const float* Wl_z = (const float*)d_in[9];
    const float* bl_z = (const float*)d_in[10];
    const float* Wl_r = (const float*)d_in[11];
    const float* bl_r = (const float*)d_in[12];
    const float* Wl_h = (const float*)d_in[13];
    const float* bl_h = (const float*)d_in[14];
    const float* W_out = (const float*)d_in[15];
    const float* b_out = (const float*)d_in[16];
    const int*   edge_index = (const int*)d_in[17];

    const int N = in_sizes[0] / 64;
    const int E = in_sizes[1];

    char* ws = (char*)d_ws;
    size_t off = 0;
    short* WT  = (short*)(ws + off); off += 7 * 4096 * 2;         // fused weights
    float* bfv = (float*)(ws + off); off += 4 * 64 * 4;           // fused biases
    off = (off + 127) & ~(size_t)127;

    int nrep = 8;                                                  // XCD count
    while (nrep > 1 && off + (size_t)nrep * N * 128 > ws_size) nrep >>= 1;
    short* AXrep = (short*)(ws + off);

    float* outY = (float*)d_out;                 // [N,64]
    float* outH = outY + (size_t)N * 64;         // [N,64]

    int n16total = nrep * N * 8;                 // replica uint4 count
    int zblk = 4096;
    prep_fuse_kernel<<<4 + zblk, 256, 0, stream>>>(
        W_z, W_r, W_h, b_z, b_r, b_h, Wl_z, Wl_r, Wl_h, bl_z, bl_r, bl_h,
        W_out, b_out, WT, bfv, AXrep, n16total);

    scatter_kernel<<<(E * 32 + 255) / 256, 256, 0, stream>>>(
        node_feat, edge_w, edge_index, AXrep, E, N, nrep - 1);

    int nblk = (N + 63) / 64;
    gates_kernel<<<nblk, 256, 0, stream>>>(AXrep, nrep, hidden,
                                           WT, bfv, outY, outH, N);
}